// Round 3
// baseline (228.271 us; speedup 1.0000x reference)
//
#include <hip/hip_runtime.h>

// CRF log-partition, MI355X — R3: single-wave blocks, barrier-free step.
// R2 counters: per-step ~640 cyc but the honest serial arithmetic is ~300;
// the rest is 4-wave s_barrier skew paid every step. This version puts each
// half-chain in ONE wave (64 lanes):
//  - lane p owns tag pair {2p, 2p+1}; computes the FULL 128-i dot for its
//    pair: 128 fdot2/lane in 8 accumulator chains (issue ~256 cyc, wave64)
//  - state = 64 packed-f16 dwords in LDS; lane reads ALL of it as 16
//    wave-uniform broadcast ds_read_b128 (conflict-free, overlaps dot issue)
//  - lane writes exactly its own pair dword (64 consecutive dwords, 2-way
//    bank aliasing = free) -> NO s_barrier, NO DPP butterfly, NO divergent
//    writer; one s_waitcnt lgkmcnt(0) orders the intra-wave RAW
//  - E tile in regs: 128 h2 (EA/EB x 64) — fits the 1-wave/SIMD 512-VGPR
//    budget (amdgpu_waves_per_eu(1,1))
// Bidi split (R2) retained: grid 128 = 64 fwd + 64 bwd half-chains, then
// crf_combine does dot(alpha_m, x_m) + log. Renorm semantics identical to
// R1/R2 (f16 exponent of state[0] folded into exp2 arg; o += eS exact).

#define LOG2E 1.4426950408889634f
#define LN2   0.6931471805599453f

#define LGKM0() asm volatile("s_waitcnt lgkmcnt(0)" ::: "memory")

typedef float    f2 __attribute__((ext_vector_type(2)));
typedef float    f4 __attribute__((ext_vector_type(4)));
typedef _Float16 h2 __attribute__((ext_vector_type(2)));

#define PKRTZ(a, b) __builtin_bit_cast(h2, __builtin_amdgcn_cvt_pkrtz((a), (b)))

__global__ __launch_bounds__(64)
__attribute__((amdgpu_waves_per_eu(1, 1)))
void crf_halves(
    const float* __restrict__ emissions,   // [64, 512, 128]
    const float* __restrict__ transitions, // [128, 128]
    const float* __restrict__ start_t,     // [128]
    const float* __restrict__ end_t,       // [128]
    const int*   __restrict__ lengths,     // [64]
    float* __restrict__ wsV,               // [2][64][128] half-vectors
    int*   __restrict__ wsO)               // [2][64] exponent accumulators
{
    constexpr int N = 128;
    constexpr int L = 512;
    const int  bid = blockIdx.x;
    const bool isf = bid < 64;
    const int  b   = isf ? bid : bid - 64;
    const int  p   = threadIdx.x;     // lane = tag pair {2p, 2p+1}

    // state: packed f16 pairs, double-buffered. All reads are wave-uniform
    // broadcasts; writes are 1 dword/lane.
    __shared__ alignas(16) float pbuf[2][64];

    // ---- E tile: EA[m] = exp of the two T entries feeding fdot2 chain slot m.
    // fwd (column-indexed): EA[m]=(e^T[2m][2p],   e^T[2m+1][2p]),
    //                       EB[m]=(e^T[2m][2p+1], e^T[2m+1][2p+1])
    // bwd (row-indexed)   : EA[m]=(e^T[2p][2m],   e^T[2p][2m+1]),
    //                       EB[m]=(e^T[2p+1][2m], e^T[2p+1][2m+1])
    h2 EA[64], EB[64];
    if (isf) {
        const float* tb = transitions + 2 * p;
        #pragma unroll
        for (int m = 0; m < 64; ++m) {
            f2 r0 = *reinterpret_cast<const f2*>(tb + (size_t)(2 * m) * N);
            f2 r1 = *reinterpret_cast<const f2*>(tb + (size_t)(2 * m + 1) * N);
            EA[m] = PKRTZ(__builtin_amdgcn_exp2f(r0.x * LOG2E),
                          __builtin_amdgcn_exp2f(r1.x * LOG2E));
            EB[m] = PKRTZ(__builtin_amdgcn_exp2f(r0.y * LOG2E),
                          __builtin_amdgcn_exp2f(r1.y * LOG2E));
        }
    } else {
        const float* ra_ = transitions + (size_t)(2 * p) * N;
        const float* rb_ = ra_ + N;
        #pragma unroll
        for (int m = 0; m < 64; ++m) {
            f2 r0 = *reinterpret_cast<const f2*>(ra_ + 2 * m);
            f2 r1 = *reinterpret_cast<const f2*>(rb_ + 2 * m);
            EA[m] = PKRTZ(__builtin_amdgcn_exp2f(r0.x * LOG2E),
                          __builtin_amdgcn_exp2f(r0.y * LOG2E));
            EB[m] = PKRTZ(__builtin_amdgcn_exp2f(r1.x * LOG2E),
                          __builtin_amdgcn_exp2f(r1.y * LOG2E));
        }
    }

    const int len = lengths[b];
    const int m   = (len - 1) >> 1;
    const float* eb = emissions + (size_t)b * L * N;

    // step schedule (identical to R2)
    int n_steps, e0, dstep; bool zfinal;
    if (isf) {
        n_steps = m; e0 = 1; dstep = 1; zfinal = false;
    } else {
        int total = len - 1 - m;
        n_steps = total > 0 ? total - 1 : 0;
        e0 = len - 2; if (e0 < 0) e0 = 0;
        dstep = -1;
        zfinal = total > 0;
    }

    // ---- init state
    int o = 0, cur = 0;
    float qA, qB;
    {
        const float* base = isf ? start_t : end_t;
        f2 bt = *reinterpret_cast<const f2*>(base + 2 * p);
        f2 ev;
        if (isf)         ev = *reinterpret_cast<const f2*>(eb + 2 * p);
        else if (zfinal) ev = *reinterpret_cast<const f2*>(eb + (size_t)(len - 1) * N + 2 * p);
        else           { ev.x = 0.f; ev.y = 0.f; }
        qA = __builtin_amdgcn_exp2f((bt.x + ev.x) * LOG2E);
        qB = __builtin_amdgcn_exp2f((bt.y + ev.y) * LOG2E);
        pbuf[0][p] = __builtin_bit_cast(float, PKRTZ(qA, qB));
    }
    LGKM0();

    auto eidx = [&](int n) {
        int nn = (n < n_steps) ? n : (n_steps - 1);
        if (nn < 0) nn = 0;
        return e0 + dstep * nn;
    };
    auto ldE = [&](int tt) {
        return *reinterpret_cast<const f2*>(eb + (size_t)tt * N + 2 * p);
    };

    auto STEP = [&](f2 ecur) {
        // 16 wave-uniform broadcast b128 reads of the whole state
        const f4* pv = reinterpret_cast<const f4*>(&pbuf[cur][0]);
        f4 P[16];
        #pragma unroll
        for (int r = 0; r < 16; ++r) P[r] = pv[r];

        // common renormalizer from state[0] (pair 0, low half = tag 0)
        unsigned u0 = __float_as_uint(P[0][0]);
        int eS = (int)((u0 >> 10) & 0x1Fu) - 15;
        o += eS;
        float feS = (float)eS;
        float esA = __builtin_amdgcn_exp2f(ecur.x * LOG2E - feS);
        float esB = __builtin_amdgcn_exp2f(ecur.y * LOG2E - feS);

        // 128 fdot2 over all 64 pair-dwords, 8 accumulator chains (depth 16)
        float aA[4] = {0.f, 0.f, 0.f, 0.f};
        float aB[4] = {0.f, 0.f, 0.f, 0.f};
        #pragma unroll
        for (int mm = 0; mm < 64; ++mm) {
            h2 pm = __builtin_bit_cast(h2, P[mm >> 2][mm & 3]);
            aA[mm & 3] = __builtin_amdgcn_fdot2(pm, EA[mm], aA[mm & 3], false);
            aB[mm & 3] = __builtin_amdgcn_fdot2(pm, EB[mm], aB[mm & 3], false);
        }
        float dA = (aA[0] + aA[1]) + (aA[2] + aA[3]);
        float dB = (aB[0] + aB[1]) + (aB[2] + aB[3]);

        qA = esA * dA;
        qB = esB * dB;
        cur ^= 1;
        pbuf[cur][p] = __builtin_bit_cast(float, PKRTZ(qA, qB));
        LGKM0();   // intra-wave RAW ordering; no s_barrier needed (1 wave)
    };

    // ---- main loop: distance-4 emission prefetch ring, 4-way unroll
    f2 ra = ldE(eidx(0));
    f2 rb = ldE(eidx(1));
    f2 rc = ldE(eidx(2));
    f2 rd = ldE(eidx(3));

    int n = 0;
    while (n < n_steps) {
        STEP(ra); ra = ldE(eidx(n + 4)); ++n; if (n >= n_steps) break;
        STEP(rb); rb = ldE(eidx(n + 4)); ++n; if (n >= n_steps) break;
        STEP(rc); rc = ldE(eidx(n + 4)); ++n; if (n >= n_steps) break;
        STEP(rd); rd = ldE(eidx(n + 4)); ++n;
    }
    if (zfinal) {              // x_m = E * w_{m+1}: zero-emission step
        f2 z; z.x = 0.f; z.y = 0.f;
        STEP(z);
    }

    // ---- write half-result: f32 pair per lane + exponent accumulator
    float* wv = wsV + (size_t)((isf ? 0 : 64) + b) * 128;
    f2 q; q.x = qA; q.y = qB;
    *reinterpret_cast<f2*>(wv + 2 * p) = q;
    if (p == 0) wsO[(isf ? 0 : 64) + b] = o;
}

__global__ __launch_bounds__(64)
void crf_combine(const float* __restrict__ wsV, const int* __restrict__ wsO,
                 const int* __restrict__ lengths, float* __restrict__ out)
{
    const int b = blockIdx.x;
    const int g = threadIdx.x;   // 64 lanes, pair {2g,2g+1}
    f2 a = *reinterpret_cast<const f2*>(wsV + (size_t)b * 128 + 2 * g);
    f2 x = *reinterpret_cast<const f2*>(wsV + (size_t)(64 + b) * 128 + 2 * g);
    float v = a.x * x.x + a.y * x.y;
    #pragma unroll
    for (int s = 1; s < 64; s <<= 1) v += __shfl_xor(v, s);
    if (g == 0)
        out[b] = LN2 * ((float)(wsO[b] + wsO[64 + b]) +
                        __builtin_amdgcn_logf(v));
}

extern "C" void kernel_launch(void* const* d_in, const int* in_sizes, int n_in,
                              void* d_out, int out_size, void* d_ws, size_t ws_size,
                              hipStream_t stream) {
    const float* emissions   = (const float*)d_in[0];
    const float* transitions = (const float*)d_in[1];
    const float* start_t     = (const float*)d_in[2];
    const float* end_t       = (const float*)d_in[3];
    const int*   lengths     = (const int*)d_in[4];
    float* out = (float*)d_out;

    float* wsV = (float*)d_ws;                                   // [2][64][128]
    int*   wsO = (int*)((char*)d_ws + 2 * 64 * 128 * sizeof(float)); // [2][64]

    crf_halves<<<dim3(128), dim3(64), 0, stream>>>(
        emissions, transitions, start_t, end_t, lengths, wsV, wsO);
    crf_combine<<<dim3(64), dim3(64), 0, stream>>>(wsV, wsO, lengths, out);
}